// Round 1
// baseline (466.528 us; speedup 1.0000x reference)
//
#include <hip/hip_runtime.h>
#include <math.h>

// Hasegawa-Wakatani 2D RHS on a 2048^2 grid, all-spectral, custom FFTs.
//
// Pipeline (7 complex 2D FFTs instead of the reference's 15):
//   A: F = fft2(n + i*omega)                       [pack trick, exact]
//   P: unpack -> build 4 packed inverse spectra:
//        S1 = i*KX'*phi + i*(i*KY'*phi)            (dphix, dphiy)
//        S2 = i*KX'*n   + i*(i*KY'*n)              (dnx, dny)
//        S3 = i*KX'*w   + i*(i*KY'*w)              (dwx, dwy)
//        S4 = Ln + i*Lw  (all linear terms: drive+couple+diffusion)
//      KX'/KY' zero the Nyquist mode: Re(ifft(i*K*f)) == ifft(i*K'*f).
//   X: ifft2(S1..S4) -> D1..D4 (each holds two real fields)
//   F: fft2(j_n + i*j_w) with bracket computed on load; dealias on store
//   G: ifft2 -> (adv_n, adv_w); final: dn = Ln - adv_n, dw = Lw - adv_w.
//
// Each 2D FFT = rowFFT (contig) -> transpose -> rowFFT (contig).
// Row FFT: 2048-pt radix-2 Stockham in LDS, 256 threads, ping-pong buffers.

#define NF 2048
#define HALF (NF/2)
#define LOGN 11
#define NT 256
#define K0F 0.15f
#define DEAL_LIM 682   // |signed index| <= floor(2/3 * 1024)

typedef float2 cplx;

__device__ __forceinline__ cplx cmul(cplx a, cplx b) {
  return make_float2(a.x*b.x - a.y*b.y, a.x*b.y + a.y*b.x);
}

// In-LDS 2048-point complex FFT (radix-2 Stockham, auto-sorting).
// SIGN=-1 forward, +1 inverse (unscaled). Data preloaded into bufA by caller
// (no barrier needed before call). Returns pointer to result buffer.
template<int SIGN>
__device__ __forceinline__ cplx* fft_row(cplx* bufA, cplx* bufB, cplx* tw) {
  const int tid = threadIdx.x;
#pragma unroll
  for (int v = 0; v < HALF/NT; ++v) {
    int u = tid + v*NT;
    float s, c;
    sincosf((float)SIGN * 6.28318530717958647692f * ((float)u * (1.0f/(float)NF)), &s, &c);
    tw[u] = make_float2(c, s);
  }
  cplx* src = bufA;
  cplx* dst = bufB;
  for (int st = 0; st < LOGN; ++st) {
    const int m = 1 << st;
    __syncthreads();
#pragma unroll
    for (int v = 0; v < HALF/NT; ++v) {
      int b = tid + v*NT;              // butterfly id 0..1023
      cplx c0 = src[b];
      cplx c1 = src[b + HALF];
      int jm = b & ~(m - 1);           // j*m -> twiddle index
      cplx w = tw[jm];
      cplx su = make_float2(c0.x + c1.x, c0.y + c1.y);
      cplx di = make_float2(c0.x - c1.x, c0.y - c1.y);
      cplx t  = cmul(di, w);
      dst[b + jm]     = su;
      dst[b + jm + m] = t;
    }
    cplx* tp = src; src = dst; dst = tp;
  }
  __syncthreads();
  return src;   // buffer written by the last stage
}

// ---- A1: load n,w real rows -> complex, forward FFT along contiguous dim
__global__ void __launch_bounds__(NT) k_fwd_pack(const float* __restrict__ nIn,
                                                 const float* __restrict__ wIn,
                                                 cplx* __restrict__ out) {
  __shared__ cplx bufA[NF], bufB[NF], tw[HALF];
  const int row = blockIdx.x;
  const float* nr = nIn + row*NF;
  const float* wr = wIn + row*NF;
  for (int c = threadIdx.x; c < NF; c += NT)
    bufA[c] = make_float2(nr[c], wr[c]);
  cplx* res = fft_row<-1>(bufA, bufB, tw);
  cplx* o = out + row*NF;
  for (int c = threadIdx.x; c < NF; c += NT) o[c] = res[c];
}

// ---- plain forward complex->complex row FFT
__global__ void __launch_bounds__(NT) k_fwd_c2c(const cplx* __restrict__ in,
                                                cplx* __restrict__ out) {
  __shared__ cplx bufA[NF], bufB[NF], tw[HALF];
  const int row = blockIdx.x;
  const cplx* ir = in + row*NF;
  for (int c = threadIdx.x; c < NF; c += NT) bufA[c] = ir[c];
  cplx* res = fft_row<-1>(bufA, bufB, tw);
  cplx* o = out + row*NF;
  for (int c = threadIdx.x; c < NF; c += NT) o[c] = res[c];
}

// ---- plain inverse complex->complex row FFT (scaled by 1/NF)
__global__ void __launch_bounds__(NT) k_inv_c2c(const cplx* __restrict__ in,
                                                cplx* __restrict__ out) {
  __shared__ cplx bufA[NF], bufB[NF], tw[HALF];
  const int row = blockIdx.x;
  const cplx* ir = in + row*NF;
  for (int c = threadIdx.x; c < NF; c += NT) bufA[c] = ir[c];
  cplx* res = fft_row<1>(bufA, bufB, tw);
  cplx* o = out + row*NF;
  const float sc = 1.0f/(float)NF;
  for (int c = threadIdx.x; c < NF; c += NT)
    o[c] = make_float2(res[c].x*sc, res[c].y*sc);
}

// ---- unpack F=fft2(n+iw) -> 4 packed spectra. Layout [ky][kx], kx contiguous.
__global__ void __launch_bounds__(NT) k_unpack(const cplx* __restrict__ F,
                                               cplx* __restrict__ S1, cplx* __restrict__ S2,
                                               cplx* __restrict__ S3, cplx* __restrict__ S4) {
  const int kx = blockIdx.x*NT + threadIdx.x;
  const int ky = blockIdx.y;
  const int idx = ky*NF + kx;
  cplx a = F[idx];
  cplx b = F[((NF - ky) & (NF-1))*NF + ((NF - kx) & (NF-1))];
  // n_hat = (F(k)+conj(F(-k)))/2 ; w_hat = (F(k)-conj(F(-k)))/(2i)
  cplx nh = make_float2(0.5f*(a.x + b.x),  0.5f*(a.y - b.y));
  cplx wh = make_float2(0.5f*(a.y + b.y), -0.5f*(a.x - b.x));
  const int sx = (kx < HALF) ? kx : kx - NF;
  const int sy = (ky < HALF) ? ky : ky - NF;
  const float kxv = K0F * (float)sx;
  const float kyv = K0F * (float)sy;
  const float k2 = kxv*kxv + kyv*kyv;
  const float pinv = (k2 > 1e-12f) ? (-1.0f/k2) : 0.0f;
  cplx ph = make_float2(wh.x*pinv, wh.y*pinv);          // phi_hat
  const float kxp = (kx == HALF) ? 0.0f : kxv;          // Nyquist-zeroed
  const float kyp = (ky == HALF) ? 0.0f : kyv;
  // pack d/dx + i*(d/dy): (-kxp*z.y - kyp*z.x, kxp*z.x - kyp*z.y)
  S1[idx] = make_float2(-kxp*ph.y - kyp*ph.x, kxp*ph.x - kyp*ph.y);
  S2[idx] = make_float2(-kxp*nh.y - kyp*nh.x, kxp*nh.x - kyp*nh.y);
  S3[idx] = make_float2(-kxp*wh.y - kyp*wh.x, kxp*wh.x - kyp*wh.y);
  // Ln = -kappa*i*kyp*ph + alpha*(ph - nh) - DN*k2*nh   (kappa=alpha=1)
  // Lw = -kappa*i*kyp*nh + alpha*(ph - nh) - DOMEGA*k2*wh
  const float dnc = 0.001f * k2;
  cplx Ln = make_float2( kyp*ph.y + (ph.x - nh.x) - dnc*nh.x,
                        -kyp*ph.x + (ph.y - nh.y) - dnc*nh.y);
  cplx Lw = make_float2( kyp*nh.y + (ph.x - nh.x) - dnc*wh.x,
                        -kyp*nh.x + (ph.y - nh.y) - dnc*wh.y);
  S4[idx] = make_float2(Ln.x - Lw.y, Ln.y + Lw.x);      // Ln + i*Lw
}

// ---- bracket on load, forward FFT. D1=(dphix,dphiy) D2=(dnx,dny) D3=(dwx,dwy)
__global__ void __launch_bounds__(NT) k_fwd_bracket(const cplx* __restrict__ D1,
                                                    const cplx* __restrict__ D2,
                                                    const cplx* __restrict__ D3,
                                                    cplx* __restrict__ out) {
  __shared__ cplx bufA[NF], bufB[NF], tw[HALF];
  const int row = blockIdx.x;
  for (int c = threadIdx.x; c < NF; c += NT) {
    cplx d1 = D1[row*NF + c];
    cplx d2 = D2[row*NF + c];
    cplx d3 = D3[row*NF + c];
    float jn = d1.x*d2.y - d1.y*d2.x;   // dphix*dny - dphiy*dnx
    float jw = d1.x*d3.y - d1.y*d3.x;
    bufA[c] = make_float2(jn, jw);
  }
  cplx* res = fft_row<-1>(bufA, bufB, tw);
  cplx* o = out + row*NF;
  for (int c = threadIdx.x; c < NF; c += NT) o[c] = res[c];
}

// ---- forward FFT with 2/3 dealias mask on store. Row index = ky.
__global__ void __launch_bounds__(NT) k_fwd_dealias(const cplx* __restrict__ in,
                                                    cplx* __restrict__ out) {
  __shared__ cplx bufA[NF], bufB[NF], tw[HALF];
  const int row = blockIdx.x;
  const cplx* ir = in + row*NF;
  for (int c = threadIdx.x; c < NF; c += NT) bufA[c] = ir[c];
  cplx* res = fft_row<-1>(bufA, bufB, tw);
  const int sy = (row < HALF) ? row : row - NF;
  const float my = ((sy < 0 ? -sy : sy) <= DEAL_LIM) ? 1.0f : 0.0f;
  cplx* o = out + row*NF;
  for (int c = threadIdx.x; c < NF; c += NT) {
    int sx = (c < HALF) ? c : c - NF;
    float m = my * (((sx < 0 ? -sx : sx) <= DEAL_LIM) ? 1.0f : 0.0f);
    o[c] = make_float2(res[c].x*m, res[c].y*m);
  }
}

// ---- final inverse pass: (adv_n, adv_w) = res/NF; combine with L=(Ln,Lw)
__global__ void __launch_bounds__(NT) k_inv_final(const cplx* __restrict__ in,
                                                  const cplx* __restrict__ L,
                                                  float* __restrict__ out) {
  __shared__ cplx bufA[NF], bufB[NF], tw[HALF];
  const int row = blockIdx.x;   // = x
  const cplx* ir = in + row*NF;
  for (int c = threadIdx.x; c < NF; c += NT) bufA[c] = ir[c];
  cplx* res = fft_row<1>(bufA, bufB, tw);
  const float sc = 1.0f/(float)NF;
  for (int c = threadIdx.x; c < NF; c += NT) {
    cplx l = L[row*NF + c];
    out[row*NF + c]         = l.x - res[c].x*sc;   // dn
    out[NF*NF + row*NF + c] = l.y - res[c].y*sc;   // dw
  }
}

// ---- tiled complex transpose
__global__ void __launch_bounds__(NT) k_transpose(const cplx* __restrict__ in,
                                                  cplx* __restrict__ out) {
  __shared__ cplx tile[32][33];
  const int tx = threadIdx.x, ty = threadIdx.y;
  int x = blockIdx.x*32 + tx;
  int y = blockIdx.y*32 + ty;
#pragma unroll
  for (int i = 0; i < 32; i += 8)
    tile[ty + i][tx] = in[(y + i)*NF + x];
  __syncthreads();
  x = blockIdx.y*32 + tx;
  y = blockIdx.x*32 + ty;
#pragma unroll
  for (int i = 0; i < 32; i += 8)
    out[(y + i)*NF + x] = tile[tx][ty + i];
}

extern "C" void kernel_launch(void* const* d_in, const int* in_sizes, int n_in,
                              void* d_out, int out_size, void* d_ws, size_t ws_size,
                              hipStream_t stream) {
  const float* nIn = (const float*)d_in[0];
  const float* wIn = (const float*)d_in[1];
  float* outF = (float*)d_out;

  const size_t B = (size_t)NF * NF * sizeof(cplx);   // 33.5 MB per complex buffer
  char* ws = (char*)d_ws;
  cplx* W0 = (cplx*)(ws);
  cplx* S1 = (cplx*)(ws + 1*B);
  cplx* S2 = (cplx*)(ws + 2*B);
  cplx* S3 = (cplx*)(ws + 3*B);
  cplx* S4 = (cplx*)(ws + 4*B);
  cplx* W1 = (cplx*)d_out;   // d_out is exactly B bytes; used as scratch, fully
                             // rewritten by k_inv_final at the end.

  dim3 bR(NT), gR(NF);
  dim3 bT(32, 8), gT(NF/32, NF/32);
  dim3 bU(NT), gU(NF/NT, NF);

  // A: F = fft2(n + i*w), final layout [ky][kx] in W0
  k_fwd_pack<<<gR, bR, 0, stream>>>(nIn, wIn, W0);     // [x][ky]
  k_transpose<<<gT, bT, 0, stream>>>(W0, W1);          // [ky][x]
  k_fwd_c2c<<<gR, bR, 0, stream>>>(W1, W0);            // [ky][kx]

  // P: unpack + build packed spectra
  k_unpack<<<gU, bU, 0, stream>>>(W0, S1, S2, S3, S4);

  // X: ifft2 of each packed spectrum -> D_i (in place of S_i), layout [x][y]
  cplx* Ss[4] = {S1, S2, S3, S4};
  for (int i = 0; i < 4; ++i) {
    k_inv_c2c<<<gR, bR, 0, stream>>>(Ss[i], W1);       // [ky][x]
    k_transpose<<<gT, bT, 0, stream>>>(W1, W0);        // [x][ky]
    k_inv_c2c<<<gR, bR, 0, stream>>>(W0, Ss[i]);       // [x][y]
  }

  // F: fft2(j_n + i*j_w), dealias on the last pass
  k_fwd_bracket<<<gR, bR, 0, stream>>>(S1, S2, S3, W0); // [x][ky]
  k_transpose<<<gT, bT, 0, stream>>>(W0, W1);           // [ky][x]
  k_fwd_dealias<<<gR, bR, 0, stream>>>(W1, W0);         // [ky][kx], masked

  // G: ifft2 -> adv; combine with D4=(Ln,Lw) and write outputs
  k_inv_c2c<<<gR, bR, 0, stream>>>(W0, W1);             // [ky][x]
  k_transpose<<<gT, bT, 0, stream>>>(W1, W0);           // [x][ky]
  k_inv_final<<<gR, bR, 0, stream>>>(W0, S4, outF);     // [x][y] -> d_out
}

// Round 2
// 287.717 us; speedup vs baseline: 1.6215x; 1.6215x over previous
//
#include <hip/hip_runtime.h>
#include <math.h>

// Hasegawa-Wakatani 2D RHS, 2048^2, all-spectral. Round 2:
//  - radix-8 Stockham FFT core (stages 8,8,8,4), inline twiddles,
//    XOR bank swizzle on all LDS indices
//  - fused kernels: fwdFFT+unpack (paired +-ky rows), 3xIFFT+bracket+fwdFFT,
//    2xIFFT+combine for the output
// 17 dispatches, ~1.34 GB HBM traffic.

#define NF 2048
#define HALF 1024
#define NT 256
#define K0F 0.15f
#define DEAL_LIM 682   // floor(2/3 * 1024)

typedef float2 cplx;

// LDS bank swizzle: fold bits 4..7 into 0..3 (cplx = 8B = 2 banks).
#define SW(i) ((i) ^ (((i) >> 4) & 15))

__device__ __forceinline__ cplx cmul(cplx a, cplx b) {
  return make_float2(a.x*b.x - a.y*b.y, a.x*b.y + a.y*b.x);
}
__device__ __forceinline__ cplx cadd(cplx a, cplx b){ return make_float2(a.x+b.x, a.y+b.y); }
__device__ __forceinline__ cplx csub(cplx a, cplx b){ return make_float2(a.x-b.x, a.y-b.y); }
template<int SIGN>
__device__ __forceinline__ cplx rot90(cplx z) {   // z * (SIGN*i)
  return (SIGN > 0) ? make_float2(-z.y, z.x) : make_float2(z.y, -z.x);
}

// One radix-8 Stockham stage: 256 butterflies, 1/thread.
// b = j*m + i; in: src[b + 256*r]; out: dst[8*j*m + i + q*m] * W^(q*j*m).
template<int SIGN>
__device__ __forceinline__ void stage8(const cplx* __restrict__ src,
                                       cplx* __restrict__ dst, int m, float ang) {
  const int b  = threadIdx.x;
  const int i  = b & (m - 1);
  const int jm = b - i;
  cplx a0 = src[SW(b)];
  cplx a1 = src[SW(b+256)];
  cplx a2 = src[SW(b+512)];
  cplx a3 = src[SW(b+768)];
  cplx a4 = src[SW(b+1024)];
  cplx a5 = src[SW(b+1280)];
  cplx a6 = src[SW(b+1536)];
  cplx a7 = src[SW(b+1792)];
  // DFT8 = two DFT4 (even/odd) + combine
  cplx t0 = cadd(a0,a4), t1 = csub(a0,a4), t2 = cadd(a2,a6), t3 = rot90<SIGN>(csub(a2,a6));
  cplx E0 = cadd(t0,t2), E2 = csub(t0,t2), E1 = cadd(t1,t3), E3 = csub(t1,t3);
  cplx u0 = cadd(a1,a5), u1 = csub(a1,a5), u2 = cadd(a3,a7), u3 = rot90<SIGN>(csub(a3,a7));
  cplx O0 = cadd(u0,u2), O2 = csub(u0,u2), O1 = cadd(u1,u3), O3 = csub(u1,u3);
  const float hh = 0.70710678118654752440f;
  O1 = cmul(O1, make_float2( hh, (float)SIGN*hh));
  O2 = rot90<SIGN>(O2);
  O3 = cmul(O3, make_float2(-hh, (float)SIGN*hh));
  cplx y0 = cadd(E0,O0), y4 = csub(E0,O0);
  cplx y1 = cadd(E1,O1), y5 = csub(E1,O1);
  cplx y2 = cadd(E2,O2), y6 = csub(E2,O2);
  cplx y3 = cadd(E3,O3), y7 = csub(E3,O3);
  float sn, cs;
  __sincosf(ang * (float)jm, &sn, &cs);
  cplx w1 = make_float2(cs, sn);
  cplx w2 = cmul(w1,w1), w3 = cmul(w2,w1), w4 = cmul(w2,w2);
  cplx w5 = cmul(w3,w2), w6 = cmul(w3,w3), w7 = cmul(w4,w3);
  const int o = 8*jm + i;
  dst[SW(o)]     = y0;
  dst[SW(o+m)]   = cmul(y1,w1);
  dst[SW(o+2*m)] = cmul(y2,w2);
  dst[SW(o+3*m)] = cmul(y3,w3);
  dst[SW(o+4*m)] = cmul(y4,w4);
  dst[SW(o+5*m)] = cmul(y5,w5);
  dst[SW(o+6*m)] = cmul(y6,w6);
  dst[SW(o+7*m)] = cmul(y7,w7);
}

// 2048-pt FFT in LDS, X in/out (Y scratch). 4 stages: R=8(m=1,8,64), R=4(m=512).
// Leading sync orders caller's X writes; trailing sync publishes result.
template<int SIGN>
__device__ __forceinline__ void fft2048(cplx* X, cplx* Y) {
  const float ang = (float)SIGN * 0.00306796157577128245957f; // 2*pi/2048
  __syncthreads();
  stage8<SIGN>(X, Y, 1, ang);
  __syncthreads();
  stage8<SIGN>(Y, X, 8, ang);
  __syncthreads();
  stage8<SIGN>(X, Y, 64, ang);
  __syncthreads();
  {
    const int tid = threadIdx.x;
#pragma unroll
    for (int v = 0; v < 2; ++v) {
      const int b = tid + v*256;
      cplx a0 = Y[SW(b)], a1 = Y[SW(b+512)], a2 = Y[SW(b+1024)], a3 = Y[SW(b+1536)];
      cplx t0 = cadd(a0,a2), t1 = csub(a0,a2), t2 = cadd(a1,a3), t3 = rot90<SIGN>(csub(a1,a3));
      X[SW(b)]      = cadd(t0,t2);
      X[SW(b+512)]  = cadd(t1,t3);
      X[SW(b+1024)] = csub(t0,t2);
      X[SW(b+1536)] = csub(t1,t3);
    }
  }
  __syncthreads();
}

// ---- load/store helpers (float4-vectorized)
__device__ __forceinline__ void ldsLoadRow(cplx* A, const cplx* g) {
  const float4* g4 = (const float4*)g;
  for (int p = threadIdx.x; p < NF/2; p += NT) {
    float4 v = g4[p];
    A[SW(2*p)]   = make_float2(v.x, v.y);
    A[SW(2*p+1)] = make_float2(v.z, v.w);
  }
}
__device__ __forceinline__ void ldsStoreRow(cplx* g, const cplx* A, float sc) {
  float4* g4 = (float4*)g;
  for (int p = threadIdx.x; p < NF/2; p += NT) {
    cplx a = A[SW(2*p)], b = A[SW(2*p+1)];
    g4[p] = make_float4(sc*a.x, sc*a.y, sc*b.x, sc*b.y);
  }
}

// ---- kernels -------------------------------------------------------------

__global__ void __launch_bounds__(NT) k_fwd_pack(const float* __restrict__ nIn,
                                                 const float* __restrict__ wIn,
                                                 cplx* __restrict__ out) {
  __shared__ cplx A[NF], B[NF];
  const int row = blockIdx.x;
  const float4* n4 = (const float4*)(nIn + (size_t)row*NF);
  const float4* w4 = (const float4*)(wIn + (size_t)row*NF);
  for (int p = threadIdx.x; p < NF/4; p += NT) {
    float4 nv = n4[p], wv = w4[p];
    A[SW(4*p)]   = make_float2(nv.x, wv.x);
    A[SW(4*p+1)] = make_float2(nv.y, wv.y);
    A[SW(4*p+2)] = make_float2(nv.z, wv.z);
    A[SW(4*p+3)] = make_float2(nv.w, wv.w);
  }
  fft2048<-1>(A, B);
  ldsStoreRow(out + (size_t)row*NF, A, 1.0f);
}

__global__ void __launch_bounds__(NT) k_inv_c2c(const cplx* __restrict__ in,
                                                cplx* __restrict__ out) {
  __shared__ cplx A[NF], B[NF];
  const int row = blockIdx.x;
  ldsLoadRow(A, in + (size_t)row*NF);
  fft2048<1>(A, B);
  ldsStoreRow(out + (size_t)row*NF, A, 1.0f/(float)NF);
}

__global__ void __launch_bounds__(NT) k_fwd_dealias(const cplx* __restrict__ in,
                                                    cplx* __restrict__ out) {
  __shared__ cplx A[NF], B[NF];
  const int row = blockIdx.x;   // = ky'
  ldsLoadRow(A, in + (size_t)row*NF);
  fft2048<-1>(A, B);
  const int sy = (row < HALF) ? row : row - NF;
  const float my = ((sy < 0 ? -sy : sy) <= DEAL_LIM) ? 1.0f : 0.0f;
  float4* g4 = (float4*)(out + (size_t)row*NF);
  for (int p = threadIdx.x; p < NF/2; p += NT) {
    int c0 = 2*p, c1 = 2*p+1;
    int sx0 = (c0 < HALF) ? c0 : c0 - NF;
    int sx1 = (c1 < HALF) ? c1 : c1 - NF;
    float m0 = my * (((sx0 < 0 ? -sx0 : sx0) <= DEAL_LIM) ? 1.0f : 0.0f);
    float m1 = my * (((sx1 < 0 ? -sx1 : sx1) <= DEAL_LIM) ? 1.0f : 0.0f);
    cplx a = A[SW(c0)], b = A[SW(c1)];
    g4[p] = make_float4(m0*a.x, m0*a.y, m1*b.x, m1*b.y);
  }
}

__device__ __forceinline__ void unpack_point(cplx a, cplx b,
    float kxv, float kyv, float kxp, float kyp,
    cplx& s1, cplx& s2, cplx& s3, cplx& s4) {
  cplx nh = make_float2(0.5f*(a.x + b.x),  0.5f*(a.y - b.y));
  cplx wh = make_float2(0.5f*(a.y + b.y), -0.5f*(a.x - b.x));
  float k2 = kxv*kxv + kyv*kyv;
  float pinv = (k2 > 1e-12f) ? (-1.0f/k2) : 0.0f;
  cplx ph = make_float2(wh.x*pinv, wh.y*pinv);
  s1 = make_float2(-kxp*ph.y - kyp*ph.x, kxp*ph.x - kyp*ph.y);
  s2 = make_float2(-kxp*nh.y - kyp*nh.x, kxp*nh.x - kyp*nh.y);
  s3 = make_float2(-kxp*wh.y - kyp*wh.x, kxp*wh.x - kyp*wh.y);
  float dnc = 0.001f * k2;
  cplx Ln = make_float2( kyp*ph.y + (ph.x - nh.x) - dnc*nh.x,
                        -kyp*ph.x + (ph.y - nh.y) - dnc*nh.y);
  cplx Lw = make_float2( kyp*nh.y + (ph.x - nh.x) - dnc*wh.x,
                        -kyp*nh.x + (ph.y - nh.y) - dnc*wh.y);
  s4 = make_float2(Ln.x - Lw.y, Ln.y + Lw.x);
}

// second forward pass + unpack, fused. Block handles rows ky and (NF-ky)&2047.
__global__ void __launch_bounds__(NT) k_fwd_unpack(const cplx* __restrict__ in,
                                                   cplx* __restrict__ S1, cplx* __restrict__ S2,
                                                   cplx* __restrict__ S3, cplx* __restrict__ S4) {
  __shared__ cplx A[NF], B[NF], C[NF];
  const int ky  = blockIdx.x;            // 0..1024
  const int ky2 = (NF - ky) & (NF - 1);
  ldsLoadRow(A, in + (size_t)ky*NF);
  fft2048<-1>(A, B);                     // F[ky][*]
  ldsLoadRow(C, in + (size_t)ky2*NF);
  fft2048<-1>(C, B);                     // F[ky2][*]
  const int syi = (ky < HALF) ? ky : ky - NF;
  const float kyv = K0F * (float)syi;
  const float kyp = (ky == HALF) ? 0.0f : kyv;
  for (int c = threadIdx.x; c < NF; c += NT) {
    const int kx = c, kx2 = (NF - kx) & (NF - 1);
    cplx a = A[SW(kx)];
    cplx b = C[SW(kx2)];
    const int sxi = (kx < HALF) ? kx : kx - NF;
    const float kxv = K0F * (float)sxi;
    const float kxp = (kx == HALF) ? 0.0f : kxv;
    cplx s1,s2,s3,s4;
    unpack_point(a, b, kxv, kyv, kxp, kyp, s1, s2, s3, s4);
    const size_t i1 = (size_t)ky*NF + kx;
    S1[i1] = s1; S2[i1] = s2; S3[i1] = s3; S4[i1] = s4;
    cplx r1,r2,r3,r4;
    unpack_point(b, a, -kxv, -kyv, -kxp, -kyp, r1, r2, r3, r4);
    const size_t i2 = (size_t)ky2*NF + kx2;
    S1[i2] = r1; S2[i2] = r2; S3[i2] = r3; S4[i2] = r4;
  }
}

// 3 final row-IFFTs + Poisson bracket + forward row FFT, fused.
__global__ void __launch_bounds__(NT) k_bracket(const cplx* __restrict__ T1,
                                                const cplx* __restrict__ T2,
                                                const cplx* __restrict__ T3,
                                                cplx* __restrict__ out) {
  __shared__ cplx A[NF], B[NF], C[NF];
  const int row = blockIdx.x;            // = x
  const size_t base = (size_t)row*NF;
  ldsLoadRow(A, T1 + base);
  fft2048<1>(A, B);                      // (dphix, dphiy) * NF
  for (int c = threadIdx.x; c < NF; c += NT) C[SW(c)] = A[SW(c)];
  ldsLoadRow(A, T2 + base);
  fft2048<1>(A, B);                      // (dnx, dny) * NF
  float jn[NF/NT];
#pragma unroll
  for (int k = 0; k < NF/NT; ++k) {
    const int c = threadIdx.x + k*NT;
    cplx dphi = C[SW(c)], dd = A[SW(c)];
    jn[k] = dphi.x*dd.y - dphi.y*dd.x;
  }
  ldsLoadRow(A, T3 + base);
  fft2048<1>(A, B);                      // (dwx, dwy) * NF
  const float sc2 = 1.0f/((float)NF*(float)NF);
#pragma unroll
  for (int k = 0; k < NF/NT; ++k) {
    const int c = threadIdx.x + k*NT;
    cplx dphi = C[SW(c)], dd = A[SW(c)];
    float jw = dphi.x*dd.y - dphi.y*dd.x;
    C[SW(c)] = make_float2(sc2*jn[k], sc2*jw);   // thread-local overwrite of dphi
  }
  fft2048<-1>(C, B);                     // fft(j_n + i*j_w) along y
  ldsStoreRow(out + base, C, 1.0f);
}

// final: row-IFFT of adv spectrum + row-IFFT of (Ln+iLw) + combine -> outputs
__global__ void __launch_bounds__(NT) k_final(const cplx* __restrict__ ADV,
                                              const cplx* __restrict__ T4,
                                              float* __restrict__ outF) {
  __shared__ cplx A[NF], B[NF], C[NF];
  const int row = blockIdx.x;            // = x
  const size_t base = (size_t)row*NF;
  ldsLoadRow(A, ADV + base);
  fft2048<1>(A, B);                      // (adv_n, adv_w) * NF
  ldsLoadRow(C, T4 + base);
  fft2048<1>(C, B);                      // (Ln, Lw) * NF
  const float sc = 1.0f/(float)NF;
  for (int c = threadIdx.x; c < NF; c += NT) {
    cplx adv = A[SW(c)], L = C[SW(c)];
    outF[base + c]                 = sc*(L.x - adv.x);   // dn
    outF[(size_t)NF*NF + base + c] = sc*(L.y - adv.y);   // dw
  }
}

__global__ void __launch_bounds__(NT) k_transpose(const cplx* __restrict__ in,
                                                  cplx* __restrict__ out) {
  __shared__ cplx tile[32][33];
  const int tx = threadIdx.x, ty = threadIdx.y;
  int x = blockIdx.x*32 + tx;
  int y = blockIdx.y*32 + ty;
#pragma unroll
  for (int i = 0; i < 32; i += 8)
    tile[ty + i][tx] = in[(size_t)(y + i)*NF + x];
  __syncthreads();
  x = blockIdx.y*32 + tx;
  y = blockIdx.x*32 + ty;
#pragma unroll
  for (int i = 0; i < 32; i += 8)
    out[(size_t)(y + i)*NF + x] = tile[tx][ty + i];
}

extern "C" void kernel_launch(void* const* d_in, const int* in_sizes, int n_in,
                              void* d_out, int out_size, void* d_ws, size_t ws_size,
                              hipStream_t stream) {
  const float* nIn = (const float*)d_in[0];
  const float* wIn = (const float*)d_in[1];
  float* outF = (float*)d_out;

  const size_t B = (size_t)NF * NF * sizeof(cplx);
  char* ws = (char*)d_ws;
  cplx* W0 = (cplx*)(ws);
  cplx* S1 = (cplx*)(ws + 1*B);
  cplx* S2 = (cplx*)(ws + 2*B);
  cplx* S3 = (cplx*)(ws + 3*B);
  cplx* S4 = (cplx*)(ws + 4*B);
  cplx* W1 = (cplx*)d_out;   // scratch until k_final overwrites it

  dim3 bR(NT), gR(NF);
  dim3 bT(32, 8), gT(NF/32, NF/32);

  // forward fft2(n + i*w): pass1 along y, transpose, pass2+unpack
  k_fwd_pack<<<gR, bR, 0, stream>>>(nIn, wIn, W0);        // [x][ky]
  k_transpose<<<gT, bT, 0, stream>>>(W0, W1);             // [ky][x]
  k_fwd_unpack<<<dim3(HALF+1), bR, 0, stream>>>(W1, S1, S2, S3, S4); // [ky][kx]

  // inverse pass 1 (along kx) + transpose for each packed spectrum
  cplx* Ss[4] = {S1, S2, S3, S4};
  for (int i = 0; i < 4; ++i) {
    k_inv_c2c<<<gR, bR, 0, stream>>>(Ss[i], W0);          // [ky][x]
    k_transpose<<<gT, bT, 0, stream>>>(W0, Ss[i]);        // [x][ky]
  }

  // bracket (finishes IFFTs of S1..S3) + forward pass along y
  k_bracket<<<gR, bR, 0, stream>>>(S1, S2, S3, W0);       // [x][ky']
  k_transpose<<<gT, bT, 0, stream>>>(W0, W1);             // [ky'][x]
  k_fwd_dealias<<<gR, bR, 0, stream>>>(W1, W0);           // [ky'][kx'], masked

  // inverse of adv spectrum: pass 1 + transpose, then fused final
  k_inv_c2c<<<gR, bR, 0, stream>>>(W0, W1);               // [ky'][x]
  k_transpose<<<gT, bT, 0, stream>>>(W1, W0);             // [x][ky']
  k_final<<<gR, bR, 0, stream>>>(W0, S4, outF);           // -> d_out
}

// Round 3
// 251.147 us; speedup vs baseline: 1.8576x; 1.1456x over previous
//
#include <hip/hip_runtime.h>
#include <math.h>

// Hasegawa-Wakatani 2D RHS, 2048^2, all-spectral. Round 3:
//  - in-place single-LDS-buffer radix-8 Stockham (16KB/row), swizzle
//    sw(i)=i^((i>>4)&15)^((i>>8)&15) breaks all stage-write stride patterns
//  - zero standalone transposes: 8-row blocks write transposed (64B segs)
//    or slab-read columns (64B segs)
//  - 10 dispatches, ~0.87 GB HBM traffic
//
// Pipeline:
//  pack_T   : n,w [x][y] --fftY, write^T--> W[ky][x]
//  unpack   : W rows (ky,-ky) --fftX--> F[ky][kx] --> S1..S4 [ky][kx]
//  inv_T x4 : S_i --ifftKX (1/N), write^T--> T_i [x][ky]
//  bracket  : T1..T3 rows --3x ifftKY, j, fftY--> BR [x][ky']
//  slab     : BR cols --fftX + 2/3 mask--> ADV [ky'][kx]
//  inv_T    : ADV --ifftKX (1/N), write^T--> ADVt [x][ky']
//  final    : ADVt,T4 rows --2x ifftKY (1/N)--> dn,dw [x][y]

#define NF 2048
#define HALF 1024
#define K0F 0.15f
#define DEAL_LIM 682

typedef float2 cplx;

__device__ __forceinline__ int sw(int i){ return i ^ ((i>>4)&15) ^ ((i>>8)&15); }

__device__ __forceinline__ cplx cmul(cplx a, cplx b){ return make_float2(a.x*b.x - a.y*b.y, a.x*b.y + a.y*b.x); }
__device__ __forceinline__ cplx cadd(cplx a, cplx b){ return make_float2(a.x+b.x, a.y+b.y); }
__device__ __forceinline__ cplx csub(cplx a, cplx b){ return make_float2(a.x-b.x, a.y-b.y); }
template<int SIGN> __device__ __forceinline__ cplx rot90(cplx z){
  return (SIGN>0)? make_float2(-z.y,z.x) : make_float2(z.y,-z.x); }

__device__ __forceinline__ void lput(cplx* L, int i, cplx v){ L[sw(i)] = v; }
__device__ __forceinline__ cplx lget(const cplx* L, int i){ return L[sw(i)]; }

// ---- in-place radix-8 stage: reads all, barrier, writes all, barrier.
template<int SIGN, int TPR, int M>
__device__ __forceinline__ void stage8_ip(cplx* X, int t) {
  constexpr int BPT = 256 / TPR;
  const float ang = (float)SIGN * 0.0030679615757712824f; // 2*pi/2048
  cplx a[BPT][8];
#pragma unroll
  for (int u = 0; u < BPT; ++u) {
    const int b = t + u * TPR;
#pragma unroll
    for (int k = 0; k < 8; ++k) a[u][k] = X[sw(b + 256 * k)];
  }
  __syncthreads();
#pragma unroll
  for (int u = 0; u < BPT; ++u) {
    const int b = t + u * TPR;
    const int i = b & (M - 1);
    const int jm = b - i;
    cplx a0=a[u][0], a1=a[u][1], a2=a[u][2], a3=a[u][3],
         a4=a[u][4], a5=a[u][5], a6=a[u][6], a7=a[u][7];
    cplx t0=cadd(a0,a4), t1=csub(a0,a4), t2=cadd(a2,a6), t3=rot90<SIGN>(csub(a2,a6));
    cplx E0=cadd(t0,t2), E2=csub(t0,t2), E1=cadd(t1,t3), E3=csub(t1,t3);
    cplx u0=cadd(a1,a5), u1=csub(a1,a5), u2=cadd(a3,a7), u3=rot90<SIGN>(csub(a3,a7));
    cplx O0=cadd(u0,u2), O2=csub(u0,u2), O1=cadd(u1,u3), O3=csub(u1,u3);
    const float hh = 0.70710678118654752440f;
    O1 = cmul(O1, make_float2(hh, (float)SIGN*hh));
    O2 = rot90<SIGN>(O2);
    O3 = cmul(O3, make_float2(-hh, (float)SIGN*hh));
    cplx y0=cadd(E0,O0), y4=csub(E0,O0);
    cplx y1=cadd(E1,O1), y5=csub(E1,O1);
    cplx y2=cadd(E2,O2), y6=csub(E2,O2);
    cplx y3=cadd(E3,O3), y7=csub(E3,O3);
    float sn, cs;
    __sincosf(ang * (float)jm, &sn, &cs);
    cplx w1 = make_float2(cs, sn);
    cplx w2 = cmul(w1,w1), w3 = cmul(w2,w1), w4 = cmul(w2,w2);
    cplx w5 = cmul(w3,w2), w6 = cmul(w3,w3), w7 = cmul(w4,w3);
    const int o = 8*jm + i;
    X[sw(o)]       = y0;
    X[sw(o+M)]     = cmul(y1,w1);
    X[sw(o+2*M)]   = cmul(y2,w2);
    X[sw(o+3*M)]   = cmul(y3,w3);
    X[sw(o+4*M)]   = cmul(y4,w4);
    X[sw(o+5*M)]   = cmul(y5,w5);
    X[sw(o+6*M)]   = cmul(y6,w6);
    X[sw(o+7*M)]   = cmul(y7,w7);
  }
  __syncthreads();
}

// ---- final radix-4 stage (m=512, j=0, twiddle-free)
template<int SIGN, int TPR>
__device__ __forceinline__ void stage4_ip(cplx* X, int t){
  constexpr int QPT = 512 / TPR;
  cplx a[QPT][4];
#pragma unroll
  for (int u=0; u<QPT; ++u){
    const int b = t + u*TPR;
#pragma unroll
    for (int k=0;k<4;++k) a[u][k] = X[sw(b + 512*k)];
  }
  __syncthreads();
#pragma unroll
  for (int u=0; u<QPT; ++u){
    const int b = t + u*TPR;
    cplx a0=a[u][0], a1=a[u][1], a2=a[u][2], a3=a[u][3];
    cplx t0=cadd(a0,a2), t1=csub(a0,a2), t2=cadd(a1,a3), t3=rot90<SIGN>(csub(a1,a3));
    X[sw(b)]       = cadd(t0,t2);
    X[sw(b+512)]   = cadd(t1,t3);
    X[sw(b+1024)]  = csub(t0,t2);
    X[sw(b+1536)]  = csub(t1,t3);
  }
  __syncthreads();
}

// entry barrier covers caller's LDS fill; exits with results published.
template<int SIGN, int TPR>
__device__ __forceinline__ void fft_ip(cplx* X, int t){
  __syncthreads();
  stage8_ip<SIGN,TPR,1>(X,t);
  stage8_ip<SIGN,TPR,8>(X,t);
  stage8_ip<SIGN,TPR,64>(X,t);
  stage4_ip<SIGN,TPR>(X,t);
}

// ---- kernels -------------------------------------------------------------

// 8 x-rows: load n,w, fft along y, transposed store -> out[ky][x]
__global__ void __launch_bounds__(1024) k_fwd_pack_T(const float* __restrict__ nIn,
                                                     const float* __restrict__ wIn,
                                                     cplx* __restrict__ out) {
  __shared__ cplx L[8*NF];
  const int tid = threadIdx.x;
  const int xb = blockIdx.x*8;
#pragma unroll
  for (int u=0; u<4; ++u){
    int f = tid + u*1024;          // 0..4095
    int r = f >> 9;                // row 0..7
    int p = f & 511;               // float4 idx
    float4 nv = ((const float4*)(nIn + (size_t)(xb+r)*NF))[p];
    float4 wv = ((const float4*)(wIn + (size_t)(xb+r)*NF))[p];
    cplx* Lr = L + r*NF;
    lput(Lr, 4*p+0, make_float2(nv.x, wv.x));
    lput(Lr, 4*p+1, make_float2(nv.y, wv.y));
    lput(Lr, 4*p+2, make_float2(nv.z, wv.z));
    lput(Lr, 4*p+3, make_float2(nv.w, wv.w));
  }
  const int row = tid >> 7, t = tid & 127;
  fft_ip<-1,128>(L + row*NF, t);
  float4* o4 = (float4*)out;
#pragma unroll
  for (int u=0; u<8; ++u){
    int f = tid + u*1024;          // 0..8191
    int ky = f >> 2;
    int xp = f & 3;
    cplx a = lget(L + (2*xp)*NF, ky);
    cplx b = lget(L + (2*xp+1)*NF, ky);
    o4[(size_t)ky*1024 + blockIdx.x*4 + xp] = make_float4(a.x,a.y,b.x,b.y);
  }
}

// 8 rows: inverse fft along contiguous dim (scale 1/N), transposed store
__global__ void __launch_bounds__(1024) k_inv_T(const cplx* __restrict__ in,
                                                cplx* __restrict__ out) {
  __shared__ cplx L[8*NF];
  const int tid = threadIdx.x;
  const int rb = blockIdx.x*8;
#pragma unroll
  for (int u=0; u<8; ++u){
    int f = tid + u*1024;
    int r = f >> 10; int p = f & 1023;
    float4 v = ((const float4*)(in + (size_t)(rb+r)*NF))[p];
    cplx* Lr = L + r*NF;
    lput(Lr, 2*p,   make_float2(v.x,v.y));
    lput(Lr, 2*p+1, make_float2(v.z,v.w));
  }
  const int row = tid >> 7, t = tid & 127;
  fft_ip<1,128>(L + row*NF, t);
  const float sc = 1.0f/(float)NF;
  float4* o4 = (float4*)out;
#pragma unroll
  for (int u=0; u<8; ++u){
    int f = tid + u*1024;
    int q = f >> 2;                // output row index of the transposed array
    int xp = f & 3;
    cplx a = lget(L + (2*xp)*NF, q);
    cplx b = lget(L + (2*xp+1)*NF, q);
    o4[(size_t)q*1024 + blockIdx.x*4 + xp] = make_float4(sc*a.x,sc*a.y,sc*b.x,sc*b.y);
  }
}

__device__ __forceinline__ void unpack_point(cplx a, cplx b,
    float kxv, float kyv, float kxp, float kyp,
    cplx& s1, cplx& s2, cplx& s3, cplx& s4) {
  cplx nh = make_float2(0.5f*(a.x + b.x),  0.5f*(a.y - b.y));
  cplx wh = make_float2(0.5f*(a.y + b.y), -0.5f*(a.x - b.x));
  float k2 = kxv*kxv + kyv*kyv;
  float pinv = (k2 > 1e-12f) ? (-1.0f/k2) : 0.0f;
  cplx ph = make_float2(wh.x*pinv, wh.y*pinv);
  s1 = make_float2(-kxp*ph.y - kyp*ph.x, kxp*ph.x - kyp*ph.y);
  s2 = make_float2(-kxp*nh.y - kyp*nh.x, kxp*nh.x - kyp*nh.y);
  s3 = make_float2(-kxp*wh.y - kyp*wh.x, kxp*wh.x - kyp*wh.y);
  float dnc = 0.001f * k2;
  cplx Ln = make_float2( kyp*ph.y + (ph.x - nh.x) - dnc*nh.x,
                        -kyp*ph.x + (ph.y - nh.y) - dnc*nh.y);
  cplx Lw = make_float2( kyp*nh.y + (ph.x - nh.x) - dnc*wh.x,
                        -kyp*nh.x + (ph.y - nh.y) - dnc*wh.y);
  s4 = make_float2(Ln.x - Lw.y, Ln.y + Lw.x);
}

// rows ky & 2048-ky: fft along x (2 concurrent FFTs), unpack -> S1..S4
__global__ void __launch_bounds__(512) k_fwd_unpack(const cplx* __restrict__ in,
                                                    cplx* __restrict__ S1, cplx* __restrict__ S2,
                                                    cplx* __restrict__ S3, cplx* __restrict__ S4) {
  __shared__ cplx A[NF], C[NF];
  const int tid = threadIdx.x;
  const int ky  = blockIdx.x;
  const int ky2 = (NF - ky) & (NF - 1);
  const int half = tid >> 8;
  const int t = tid & 255;
  {
    cplx* L = half ? C : A;
    const cplx* g = in + (size_t)(half ? ky2 : ky)*NF;
#pragma unroll
    for (int u=0; u<4; ++u){
      int p = t + u*256;
      float4 v = ((const float4*)g)[p];
      lput(L, 2*p,   make_float2(v.x,v.y));
      lput(L, 2*p+1, make_float2(v.z,v.w));
    }
    fft_ip<-1,256>(L, t);
  }
  const int syi = (ky < HALF) ? ky : ky - NF;
  const float kyv = K0F * (float)syi;
  const float kyp = (ky == HALF) ? 0.0f : kyv;
  for (int c = tid; c < NF; c += 512) {
    const int kx = c, kx2 = (NF - kx) & (NF - 1);
    cplx a = lget(A, kx);
    cplx b = lget(C, kx2);
    const int sxi = (kx < HALF) ? kx : kx - NF;
    const float kxv = K0F * (float)sxi;
    const float kxp = (kx == HALF) ? 0.0f : kxv;
    cplx s1,s2,s3,s4;
    unpack_point(a, b, kxv, kyv, kxp, kyp, s1, s2, s3, s4);
    const size_t i1 = (size_t)ky*NF + kx;
    S1[i1] = s1; S2[i1] = s2; S3[i1] = s3; S4[i1] = s4;
    cplx r1,r2,r3,r4;
    unpack_point(b, a, -kxv, -kyv, -kxp, -kyp, r1, r2, r3, r4);
    const size_t i2 = (size_t)ky2*NF + kx2;
    S1[i2] = r1; S2[i2] = r2; S3[i2] = r3; S4[i2] = r4;
  }
}

// 2 x-rows: 3x ifft along ky, bracket, fwd fft along y -> BR[x][ky']
__global__ void __launch_bounds__(512) k_bracket(const cplx* __restrict__ T1,
                                                 const cplx* __restrict__ T2,
                                                 const cplx* __restrict__ T3,
                                                 cplx* __restrict__ out) {
  __shared__ cplx A[2][NF], C[2][NF];
  const int tid = threadIdx.x;
  const int r = tid >> 8;
  const int t = tid & 255;
  const size_t base = ((size_t)blockIdx.x*2 + r)*NF;
  cplx* Ar = A[r]; cplx* Cr = C[r];
#pragma unroll
  for (int u=0; u<4; ++u){
    int p = t + u*256;
    float4 v = ((const float4*)(T1 + base))[p];
    lput(Cr, 2*p, make_float2(v.x,v.y)); lput(Cr, 2*p+1, make_float2(v.z,v.w));
  }
  fft_ip<1,256>(Cr, t);                    // (dphix,dphiy)*N in C
#pragma unroll
  for (int u=0; u<4; ++u){
    int p = t + u*256;
    float4 v = ((const float4*)(T2 + base))[p];
    lput(Ar, 2*p, make_float2(v.x,v.y)); lput(Ar, 2*p+1, make_float2(v.z,v.w));
  }
  fft_ip<1,256>(Ar, t);                    // (dnx,dny)*N in A
  float jn[8];
#pragma unroll
  for (int u=0; u<8; ++u){
    int c = t + u*256;
    cplx dphi = lget(Cr, c), dd = lget(Ar, c);
    jn[u] = dphi.x*dd.y - dphi.y*dd.x;
  }
  __syncthreads();                          // all jn reads of A done
#pragma unroll
  for (int u=0; u<4; ++u){
    int p = t + u*256;
    float4 v = ((const float4*)(T3 + base))[p];
    lput(Ar, 2*p, make_float2(v.x,v.y)); lput(Ar, 2*p+1, make_float2(v.z,v.w));
  }
  fft_ip<1,256>(Ar, t);                    // (dwx,dwy)*N in A
  const float sc2 = 1.0f/((float)NF*(float)NF);
#pragma unroll
  for (int u=0; u<8; ++u){
    int c = t + u*256;
    cplx dphi = lget(Cr, c), dd = lget(Ar, c);
    float jw = dphi.x*dd.y - dphi.y*dd.x;
    lput(Cr, c, make_float2(sc2*jn[u], sc2*jw));   // own slot r/w
  }
  fft_ip<-1,256>(Cr, t);                   // fft(j_n + i*j_w) along y
  float4* o4 = (float4*)(out + base);
#pragma unroll
  for (int u=0; u<4; ++u){
    int p = t + u*256;
    cplx a = lget(Cr, 2*p), b = lget(Cr, 2*p+1);
    o4[p] = make_float4(a.x,a.y,b.x,b.y);
  }
}

// 8 ky'-columns slab: read 64B segs, fft along x, 2/3 mask, -> ADV[ky'][kx]
__global__ void __launch_bounds__(1024) k_dealias_slab(const cplx* __restrict__ in,
                                                       cplx* __restrict__ out) {
  __shared__ cplx L[8*NF];
  const int tid = threadIdx.x;
  const int cb = blockIdx.x*8;
#pragma unroll
  for (int u=0; u<8; ++u){
    int f = tid + u*1024;
    int x = f >> 2; int j = f & 3;
    float4 v = ((const float4*)(in + (size_t)x*NF + cb))[j];
    lput(L + (2*j)*NF,   x, make_float2(v.x,v.y));
    lput(L + (2*j+1)*NF, x, make_float2(v.z,v.w));
  }
  const int row = tid >> 7, t = tid & 127;
  fft_ip<-1,128>(L + row*NF, t);
#pragma unroll
  for (int u=0; u<8; ++u){
    int f = tid + u*1024;
    int c = f >> 10; int p = f & 1023;
    int ky = cb + c;
    int sy = (ky < HALF) ? ky : ky - NF;
    float my = ((sy < 0 ? -sy : sy) <= DEAL_LIM) ? 1.0f : 0.0f;
    int k0 = 2*p, k1 = 2*p+1;
    int sx0 = (k0 < HALF) ? k0 : k0 - NF;
    int sx1 = (k1 < HALF) ? k1 : k1 - NF;
    float m0 = my * (((sx0 < 0 ? -sx0 : sx0) <= DEAL_LIM) ? 1.0f : 0.0f);
    float m1 = my * (((sx1 < 0 ? -sx1 : sx1) <= DEAL_LIM) ? 1.0f : 0.0f);
    cplx a = lget(L + c*NF, k0), b = lget(L + c*NF, k1);
    ((float4*)(out + (size_t)ky*NF))[p] = make_float4(m0*a.x,m0*a.y,m1*b.x,m1*b.y);
  }
}

// 2 x-rows: ifft ADVt and T4 along ky, combine -> dn,dw
__global__ void __launch_bounds__(512) k_final(const cplx* __restrict__ ADVt,
                                               const cplx* __restrict__ T4,
                                               float* __restrict__ outF) {
  __shared__ cplx A[2][NF], C[2][NF];
  const int tid = threadIdx.x;
  const int r = tid >> 8;
  const int t = tid & 255;
  const size_t base = ((size_t)blockIdx.x*2 + r)*NF;
  cplx* Ar = A[r]; cplx* Cr = C[r];
#pragma unroll
  for (int u=0; u<4; ++u){
    int p = t + u*256;
    float4 v = ((const float4*)(ADVt + base))[p];
    lput(Ar, 2*p, make_float2(v.x,v.y)); lput(Ar, 2*p+1, make_float2(v.z,v.w));
  }
  fft_ip<1,256>(Ar, t);                    // adv*N
#pragma unroll
  for (int u=0; u<4; ++u){
    int p = t + u*256;
    float4 v = ((const float4*)(T4 + base))[p];
    lput(Cr, 2*p, make_float2(v.x,v.y)); lput(Cr, 2*p+1, make_float2(v.z,v.w));
  }
  fft_ip<1,256>(Cr, t);                    // (Ln,Lw)*N
  const float sc = 1.0f/(float)NF;
  const size_t NSQ = (size_t)NF*NF;
#pragma unroll
  for (int u=0; u<2; ++u){
    int p = t + u*256;                     // float4 idx 0..511
    int y = 4*p;
    cplx A0=lget(Ar,y), A1=lget(Ar,y+1), A2=lget(Ar,y+2), A3=lget(Ar,y+3);
    cplx C0=lget(Cr,y), C1=lget(Cr,y+1), C2=lget(Cr,y+2), C3=lget(Cr,y+3);
    ((float4*)(outF + base))[p] =
      make_float4(sc*(C0.x-A0.x), sc*(C1.x-A1.x), sc*(C2.x-A2.x), sc*(C3.x-A3.x));
    ((float4*)(outF + NSQ + base))[p] =
      make_float4(sc*(C0.y-A0.y), sc*(C1.y-A1.y), sc*(C2.y-A2.y), sc*(C3.y-A3.y));
  }
}

extern "C" void kernel_launch(void* const* d_in, const int* in_sizes, int n_in,
                              void* d_out, int out_size, void* d_ws, size_t ws_size,
                              hipStream_t stream) {
  const float* nIn = (const float*)d_in[0];
  const float* wIn = (const float*)d_in[1];
  float* outF = (float*)d_out;

  const size_t B = (size_t)NF * NF * sizeof(cplx);
  char* ws = (char*)d_ws;
  cplx* ws0 = (cplx*)(ws);
  cplx* ws1 = (cplx*)(ws + 1*B);
  cplx* ws2 = (cplx*)(ws + 2*B);
  cplx* ws3 = (cplx*)(ws + 3*B);
  cplx* ws4 = (cplx*)(ws + 4*B);
  cplx* dscr = (cplx*)d_out;   // scratch until k_final overwrites it

  // forward: pack+fftY (write^T), then fftX+unpack
  k_fwd_pack_T <<<256, 1024, 0, stream>>>(nIn, wIn, ws0);          // W[ky][x]
  k_fwd_unpack <<<HALF+1, 512, 0, stream>>>(ws0, ws1, ws2, ws3, ws4); // S1..S4 [ky][kx]

  // inverse pass 1 + transposed store for each packed spectrum
  k_inv_T <<<256, 1024, 0, stream>>>(ws1, ws0);    // T1 [x][ky]
  k_inv_T <<<256, 1024, 0, stream>>>(ws2, dscr);   // T2
  k_inv_T <<<256, 1024, 0, stream>>>(ws3, ws1);    // T3
  k_inv_T <<<256, 1024, 0, stream>>>(ws4, ws2);    // T4

  // bracket (finishes ifftY) + fwd fftY -> BR [x][ky']
  k_bracket <<<1024, 512, 0, stream>>>(ws0, dscr, ws1, ws3);

  // fwd fftX over columns + dealias -> ADV [ky'][kx]
  k_dealias_slab <<<256, 1024, 0, stream>>>(ws3, ws4);

  // inverse pass 1 of ADV + transposed store -> ADVt [x][ky']
  k_inv_T <<<256, 1024, 0, stream>>>(ws4, ws0);

  // final: ifftY of ADVt & T4, combine -> d_out
  k_final <<<1024, 512, 0, stream>>>(ws0, ws2, outF);
}

// Round 4
// 205.427 us; speedup vs baseline: 2.2710x; 1.2226x over previous
//
#include <hip/hip_runtime.h>
#include <math.h>

// Hasegawa-Wakatani 2D RHS, 2048^2, all-spectral. Round 4:
//  - all big kernels 64KB LDS (2 blocks/CU) or 16KB (4-8 blocks/CU)
//  - bracket/final: single 16KB buffer/row, dphi/adv held in registers
//  - slab kernel fuses fftX + 2/3 mask + ifftX (kills one 67MB pass)
//  - chunked XCD swizzle heals 32B transposed-write segments
// 7 dispatches, ~804 MB HBM traffic.
//
// Pipeline:
//  pack_T : n,w [x][y] --fftY, write^T--> W[ky][x]
//  unpack : W rows (ky,-ky) --fftX--> F --> S1..S4 [ky][kx]
//  inv2 x2: S_i --ifftKX (1/N), write^T--> T_i [x][ky]
//  bracket: T1..T3 rows --3x ifftKY(regs trick), j, fftY--> BR [x][ky']
//  slabX  : BR cols --fftX, mask*(1/N), ifftX, write^T--> ADVt [x][ky']
//  final  : ADVt,T4 rows --2x ifftKY (regs trick), combine--> dn,dw [x][y]

#define NF 2048
#define HALF 1024
#define K0F 0.15f
#define DEAL_LIM 682

typedef float2 cplx;

__device__ __forceinline__ int sw(int i){ return i ^ ((i>>4)&15) ^ ((i>>8)&15); }
__device__ __forceinline__ cplx cmul(cplx a, cplx b){ return make_float2(a.x*b.x - a.y*b.y, a.x*b.y + a.y*b.x); }
__device__ __forceinline__ cplx cadd(cplx a, cplx b){ return make_float2(a.x+b.x, a.y+b.y); }
__device__ __forceinline__ cplx csub(cplx a, cplx b){ return make_float2(a.x-b.x, a.y-b.y); }
template<int SIGN> __device__ __forceinline__ cplx rot90(cplx z){
  return (SIGN>0)? make_float2(-z.y,z.x) : make_float2(z.y,-z.x); }
__device__ __forceinline__ void lput(cplx* L, int i, cplx v){ L[sw(i)] = v; }
__device__ __forceinline__ cplx lget(const cplx* L, int i){ return L[sw(i)]; }

// chunked XCD swizzle (grid % 8 == 0): consecutive logical blocks -> same XCD
__device__ __forceinline__ int xcd_chunk(int bid, int nwg){
  return (bid & 7) * (nwg >> 3) + (bid >> 3);
}

// ---- in-place radix-8 stage: read all, barrier, write all, barrier.
template<int SIGN, int TPR, int M>
__device__ __forceinline__ void stage8_ip(cplx* X, int t) {
  constexpr int BPT = 256 / TPR;
  const float ang = (float)SIGN * 0.0030679615757712824f; // 2*pi/2048
  cplx a[BPT][8];
#pragma unroll
  for (int u = 0; u < BPT; ++u) {
    const int b = t + u * TPR;
#pragma unroll
    for (int k = 0; k < 8; ++k) a[u][k] = X[sw(b + 256 * k)];
  }
  __syncthreads();
#pragma unroll
  for (int u = 0; u < BPT; ++u) {
    const int b = t + u * TPR;
    const int i = b & (M - 1);
    const int jm = b - i;
    cplx a0=a[u][0], a1=a[u][1], a2=a[u][2], a3=a[u][3],
         a4=a[u][4], a5=a[u][5], a6=a[u][6], a7=a[u][7];
    cplx t0=cadd(a0,a4), t1=csub(a0,a4), t2=cadd(a2,a6), t3=rot90<SIGN>(csub(a2,a6));
    cplx E0=cadd(t0,t2), E2=csub(t0,t2), E1=cadd(t1,t3), E3=csub(t1,t3);
    cplx u0=cadd(a1,a5), u1=csub(a1,a5), u2=cadd(a3,a7), u3=rot90<SIGN>(csub(a3,a7));
    cplx O0=cadd(u0,u2), O2=csub(u0,u2), O1=cadd(u1,u3), O3=csub(u1,u3);
    const float hh = 0.70710678118654752440f;
    O1 = cmul(O1, make_float2(hh, (float)SIGN*hh));
    O2 = rot90<SIGN>(O2);
    O3 = cmul(O3, make_float2(-hh, (float)SIGN*hh));
    cplx y0=cadd(E0,O0), y4=csub(E0,O0);
    cplx y1=cadd(E1,O1), y5=csub(E1,O1);
    cplx y2=cadd(E2,O2), y6=csub(E2,O2);
    cplx y3=cadd(E3,O3), y7=csub(E3,O3);
    float sn, cs;
    __sincosf(ang * (float)jm, &sn, &cs);
    cplx w1 = make_float2(cs, sn);
    cplx w2 = cmul(w1,w1), w3 = cmul(w2,w1), w4 = cmul(w2,w2);
    cplx w5 = cmul(w3,w2), w6 = cmul(w3,w3), w7 = cmul(w4,w3);
    const int o = 8*jm + i;
    X[sw(o)]       = y0;
    X[sw(o+M)]     = cmul(y1,w1);
    X[sw(o+2*M)]   = cmul(y2,w2);
    X[sw(o+3*M)]   = cmul(y3,w3);
    X[sw(o+4*M)]   = cmul(y4,w4);
    X[sw(o+5*M)]   = cmul(y5,w5);
    X[sw(o+6*M)]   = cmul(y6,w6);
    X[sw(o+7*M)]   = cmul(y7,w7);
  }
  __syncthreads();
}

template<int SIGN, int TPR>
__device__ __forceinline__ void stage4_ip(cplx* X, int t){
  constexpr int QPT = 512 / TPR;
  cplx a[QPT][4];
#pragma unroll
  for (int u=0; u<QPT; ++u){
    const int b = t + u*TPR;
#pragma unroll
    for (int k=0;k<4;++k) a[u][k] = X[sw(b + 512*k)];
  }
  __syncthreads();
#pragma unroll
  for (int u=0; u<QPT; ++u){
    const int b = t + u*TPR;
    cplx a0=a[u][0], a1=a[u][1], a2=a[u][2], a3=a[u][3];
    cplx t0=cadd(a0,a2), t1=csub(a0,a2), t2=cadd(a1,a3), t3=rot90<SIGN>(csub(a1,a3));
    X[sw(b)]       = cadd(t0,t2);
    X[sw(b+512)]   = cadd(t1,t3);
    X[sw(b+1024)]  = csub(t0,t2);
    X[sw(b+1536)]  = csub(t1,t3);
  }
  __syncthreads();
}

// entry barrier covers caller's LDS fill; exits with results published.
template<int SIGN, int TPR>
__device__ __forceinline__ void fft_ip(cplx* X, int t){
  __syncthreads();
  stage8_ip<SIGN,TPR,1>(X,t);
  stage8_ip<SIGN,TPR,8>(X,t);
  stage8_ip<SIGN,TPR,64>(X,t);
  stage4_ip<SIGN,TPR>(X,t);
}

// ---- kernels -------------------------------------------------------------

// 4 x-rows: load n,w, fft along y, transposed store -> out[ky][x]
__global__ void __launch_bounds__(512) k_fwd_pack_T(const float* __restrict__ nIn,
                                                    const float* __restrict__ wIn,
                                                    cplx* __restrict__ out) {
  __shared__ cplx L[4*NF];
  const int tid = threadIdx.x;
  const int lb = xcd_chunk(blockIdx.x, gridDim.x);
  const int xb = lb*4;
#pragma unroll
  for (int u=0; u<4; ++u){
    int f = tid + u*512;           // 0..2047
    int r = f >> 9;                // row 0..3
    int p = f & 511;               // float4 idx
    float4 nv = ((const float4*)(nIn + (size_t)(xb+r)*NF))[p];
    float4 wv = ((const float4*)(wIn + (size_t)(xb+r)*NF))[p];
    cplx* Lr = L + r*NF;
    lput(Lr, 4*p+0, make_float2(nv.x, wv.x));
    lput(Lr, 4*p+1, make_float2(nv.y, wv.y));
    lput(Lr, 4*p+2, make_float2(nv.z, wv.z));
    lput(Lr, 4*p+3, make_float2(nv.w, wv.w));
  }
  const int row = tid >> 7, t = tid & 127;
  fft_ip<-1,128>(L + row*NF, t);
  float4* o4 = (float4*)out;
#pragma unroll
  for (int u=0; u<8; ++u){
    int f = tid + u*512;           // 0..4095
    int ky = f >> 1;
    int xp = f & 1;                // local x-pair
    cplx a = lget(L + (2*xp)*NF, ky);
    cplx b = lget(L + (2*xp+1)*NF, ky);
    o4[(size_t)ky*(NF/2) + lb*2 + xp] = make_float4(a.x,a.y,b.x,b.y);
  }
}

// 4 rows x 2 arrays: ifft along contiguous dim (1/N), transposed store
__global__ void __launch_bounds__(512) k_inv2(const cplx* __restrict__ in0,
                                              const cplx* __restrict__ in1,
                                              cplx* __restrict__ out0,
                                              cplx* __restrict__ out1) {
  __shared__ cplx L[4*NF];
  const int tid = threadIdx.x;
  const int lb = xcd_chunk(blockIdx.x, gridDim.x);
  const cplx* in = blockIdx.y ? in1 : in0;
  cplx* out = blockIdx.y ? out1 : out0;
  const int rb = lb*4;
#pragma unroll
  for (int u=0; u<8; ++u){
    int f = tid + u*512;           // 0..4095
    int r = f >> 10, p = f & 1023;
    float4 v = ((const float4*)(in + (size_t)(rb+r)*NF))[p];
    cplx* Lr = L + r*NF;
    lput(Lr, 2*p,   make_float2(v.x,v.y));
    lput(Lr, 2*p+1, make_float2(v.z,v.w));
  }
  const int row = tid >> 7, t = tid & 127;
  fft_ip<1,128>(L + row*NF, t);
  const float sc = 1.0f/(float)NF;
  float4* o4 = (float4*)out;
#pragma unroll
  for (int u=0; u<8; ++u){
    int f = tid + u*512;
    int q = f >> 1;                // transposed output row
    int xp = f & 1;
    cplx a = lget(L + (2*xp)*NF, q);
    cplx b = lget(L + (2*xp+1)*NF, q);
    o4[(size_t)q*(NF/2) + lb*2 + xp] = make_float4(sc*a.x,sc*a.y,sc*b.x,sc*b.y);
  }
}

__device__ __forceinline__ void unpack_point(cplx a, cplx b,
    float kxv, float kyv, float kxp, float kyp,
    cplx& s1, cplx& s2, cplx& s3, cplx& s4) {
  cplx nh = make_float2(0.5f*(a.x + b.x),  0.5f*(a.y - b.y));
  cplx wh = make_float2(0.5f*(a.y + b.y), -0.5f*(a.x - b.x));
  float k2 = kxv*kxv + kyv*kyv;
  float pinv = (k2 > 1e-12f) ? (-1.0f/k2) : 0.0f;
  cplx ph = make_float2(wh.x*pinv, wh.y*pinv);
  s1 = make_float2(-kxp*ph.y - kyp*ph.x, kxp*ph.x - kyp*ph.y);
  s2 = make_float2(-kxp*nh.y - kyp*nh.x, kxp*nh.x - kyp*nh.y);
  s3 = make_float2(-kxp*wh.y - kyp*wh.x, kxp*wh.x - kyp*wh.y);
  float dnc = 0.001f * k2;
  cplx Ln = make_float2( kyp*ph.y + (ph.x - nh.x) - dnc*nh.x,
                        -kyp*ph.x + (ph.y - nh.y) - dnc*nh.y);
  cplx Lw = make_float2( kyp*nh.y + (ph.x - nh.x) - dnc*wh.x,
                        -kyp*nh.x + (ph.y - nh.y) - dnc*wh.y);
  s4 = make_float2(Ln.x - Lw.y, Ln.y + Lw.x);
}

// rows ky & 2048-ky: fft along x (2 concurrent FFTs), unpack -> S1..S4
__global__ void __launch_bounds__(512) k_fwd_unpack(const cplx* __restrict__ in,
                                                    cplx* __restrict__ S1, cplx* __restrict__ S2,
                                                    cplx* __restrict__ S3, cplx* __restrict__ S4) {
  __shared__ cplx A[NF], C[NF];
  const int tid = threadIdx.x;
  const int ky  = blockIdx.x;
  const int ky2 = (NF - ky) & (NF - 1);
  const int half = tid >> 8;
  const int t = tid & 255;
  {
    cplx* L = half ? C : A;
    const cplx* g = in + (size_t)(half ? ky2 : ky)*NF;
#pragma unroll
    for (int u=0; u<4; ++u){
      int p = t + u*256;
      float4 v = ((const float4*)g)[p];
      lput(L, 2*p,   make_float2(v.x,v.y));
      lput(L, 2*p+1, make_float2(v.z,v.w));
    }
    fft_ip<-1,256>(L, t);
  }
  const int syi = (ky < HALF) ? ky : ky - NF;
  const float kyv = K0F * (float)syi;
  const float kyp = (ky == HALF) ? 0.0f : kyv;
  for (int c = tid; c < NF; c += 512) {
    const int kx = c, kx2 = (NF - kx) & (NF - 1);
    cplx a = lget(A, kx);
    cplx b = lget(C, kx2);
    const int sxi = (kx < HALF) ? kx : kx - NF;
    const float kxv = K0F * (float)sxi;
    const float kxp = (kx == HALF) ? 0.0f : kxv;
    cplx s1,s2,s3,s4;
    unpack_point(a, b, kxv, kyv, kxp, kyp, s1, s2, s3, s4);
    const size_t i1 = (size_t)ky*NF + kx;
    S1[i1] = s1; S2[i1] = s2; S3[i1] = s3; S4[i1] = s4;
    cplx r1,r2,r3,r4;
    unpack_point(b, a, -kxv, -kyv, -kxp, -kyp, r1, r2, r3, r4);
    const size_t i2 = (size_t)ky2*NF + kx2;
    S1[i2] = r1; S2[i2] = r2; S3[i2] = r3; S4[i2] = r4;
  }
}

// 1 x-row, 16KB: 3x ifft along ky (dphi in regs), bracket, fwd fft -> BR[x][ky']
__global__ void __launch_bounds__(256) k_bracket(const cplx* __restrict__ T1,
                                                 const cplx* __restrict__ T2,
                                                 const cplx* __restrict__ T3,
                                                 cplx* __restrict__ out) {
  __shared__ cplx A[NF];
  const int t = threadIdx.x;
  const size_t base = (size_t)blockIdx.x * NF;
#pragma unroll
  for (int u=0; u<4; ++u){
    int p = t + u*256;
    float4 v = ((const float4*)(T1 + base))[p];
    lput(A, 2*p, make_float2(v.x,v.y)); lput(A, 2*p+1, make_float2(v.z,v.w));
  }
  fft_ip<1,256>(A, t);                  // (dphix,dphiy)*N
  cplx dphi[8];
#pragma unroll
  for (int u=0; u<8; ++u) dphi[u] = lget(A, t + u*256);
  __syncthreads();
#pragma unroll
  for (int u=0; u<4; ++u){
    int p = t + u*256;
    float4 v = ((const float4*)(T2 + base))[p];
    lput(A, 2*p, make_float2(v.x,v.y)); lput(A, 2*p+1, make_float2(v.z,v.w));
  }
  fft_ip<1,256>(A, t);                  // (dnx,dny)*N
  float jn[8];
#pragma unroll
  for (int u=0; u<8; ++u){
    cplx dd = lget(A, t + u*256);
    jn[u] = dphi[u].x*dd.y - dphi[u].y*dd.x;
  }
  __syncthreads();
#pragma unroll
  for (int u=0; u<4; ++u){
    int p = t + u*256;
    float4 v = ((const float4*)(T3 + base))[p];
    lput(A, 2*p, make_float2(v.x,v.y)); lput(A, 2*p+1, make_float2(v.z,v.w));
  }
  fft_ip<1,256>(A, t);                  // (dwx,dwy)*N
  const float sc2 = 1.0f/((float)NF*(float)NF);
#pragma unroll
  for (int u=0; u<8; ++u){
    int c = t + u*256;
    cplx dd = lget(A, c);
    float jw = dphi[u].x*dd.y - dphi[u].y*dd.x;
    lput(A, c, make_float2(sc2*jn[u], sc2*jw));   // own-slot r/w
  }
  fft_ip<-1,256>(A, t);                 // fft(j_n + i*j_w) along y
  float4* o4 = (float4*)(out + base);
#pragma unroll
  for (int u=0; u<4; ++u){
    int p = t + u*256;
    cplx a = lget(A, 2*p), b = lget(A, 2*p+1);
    o4[p] = make_float4(a.x,a.y,b.x,b.y);
  }
}

// 4 ky'-columns: fftX, 2/3 mask * (1/N), ifftX, transposed write [x][ky']
__global__ void __launch_bounds__(512) k_slabX(const cplx* __restrict__ in,
                                               cplx* __restrict__ out) {
  __shared__ cplx L[4*NF];
  const int tid = threadIdx.x;
  const int lb = xcd_chunk(blockIdx.x, gridDim.x);
  const int cb = lb*4;
#pragma unroll
  for (int u=0; u<8; ++u){
    int f = tid + u*512;           // 0..4095
    int x = f >> 1, j = f & 1;
    float4 v = ((const float4*)(in + (size_t)x*NF + cb))[j];
    lput(L + (2*j)*NF,   x, make_float2(v.x,v.y));
    lput(L + (2*j+1)*NF, x, make_float2(v.z,v.w));
  }
  const int row = tid >> 7, t = tid & 127;
  fft_ip<-1,128>(L + row*NF, t);
  const float sc = 1.0f/(float)NF;
#pragma unroll
  for (int v2=0; v2<16; ++v2){
    int g = tid + v2*512;          // 0..8191
    int c = g >> 11, kk = g & 2047;
    int ky = cb + c;
    int sy = (ky < HALF) ? ky : ky - NF;
    int sx = (kk < HALF) ? kk : kk - NF;
    float m = (((sy<0?-sy:sy) <= DEAL_LIM) && ((sx<0?-sx:sx) <= DEAL_LIM)) ? sc : 0.0f;
    cplx z = lget(L + c*NF, kk);
    lput(L + c*NF, kk, make_float2(m*z.x, m*z.y));   // own-slot r/w
  }
  fft_ip<1,128>(L + row*NF, t);
#pragma unroll
  for (int u=0; u<8; ++u){
    int f = tid + u*512;
    int x = f >> 1, j = f & 1;
    cplx a = lget(L + (2*j)*NF, x);
    cplx b = lget(L + (2*j+1)*NF, x);
    ((float4*)(out + (size_t)x*NF + cb))[j] = make_float4(a.x,a.y,b.x,b.y);
  }
}

// 1 x-row, 16KB: ifft ADVt (adv in regs), ifft T4, combine -> dn,dw
__global__ void __launch_bounds__(256) k_final(const cplx* __restrict__ ADVt,
                                               const cplx* __restrict__ T4,
                                               float* __restrict__ outF) {
  __shared__ cplx A[NF];
  const int t = threadIdx.x;
  const size_t base = (size_t)blockIdx.x * NF;
#pragma unroll
  for (int u=0; u<4; ++u){
    int p = t + u*256;
    float4 v = ((const float4*)(ADVt + base))[p];
    lput(A, 2*p, make_float2(v.x,v.y)); lput(A, 2*p+1, make_float2(v.z,v.w));
  }
  fft_ip<1,256>(A, t);                  // adv*N
  cplx adv[8];
#pragma unroll
  for (int u=0; u<8; ++u) adv[u] = lget(A, t + u*256);
  __syncthreads();
#pragma unroll
  for (int u=0; u<4; ++u){
    int p = t + u*256;
    float4 v = ((const float4*)(T4 + base))[p];
    lput(A, 2*p, make_float2(v.x,v.y)); lput(A, 2*p+1, make_float2(v.z,v.w));
  }
  fft_ip<1,256>(A, t);                  // (Ln,Lw)*N
  const float sc = 1.0f/(float)NF;
  const size_t NSQ = (size_t)NF*NF;
#pragma unroll
  for (int u=0; u<8; ++u){
    int c = t + u*256;
    cplx Lv = lget(A, c);
    outF[base + c]       = sc*(Lv.x - adv[u].x);   // dn
    outF[NSQ + base + c] = sc*(Lv.y - adv[u].y);   // dw
  }
}

extern "C" void kernel_launch(void* const* d_in, const int* in_sizes, int n_in,
                              void* d_out, int out_size, void* d_ws, size_t ws_size,
                              hipStream_t stream) {
  const float* nIn = (const float*)d_in[0];
  const float* wIn = (const float*)d_in[1];
  float* outF = (float*)d_out;

  const size_t B = (size_t)NF * NF * sizeof(cplx);
  char* ws = (char*)d_ws;
  cplx* ws0 = (cplx*)(ws);
  cplx* ws1 = (cplx*)(ws + 1*B);
  cplx* ws2 = (cplx*)(ws + 2*B);
  cplx* ws3 = (cplx*)(ws + 3*B);
  cplx* ws4 = (cplx*)(ws + 4*B);
  cplx* dscr = (cplx*)d_out;   // scratch until k_final overwrites it

  // forward: pack+fftY (write^T), then fftX+unpack
  k_fwd_pack_T <<<512, 512, 0, stream>>>(nIn, wIn, ws0);              // W[ky][x]
  k_fwd_unpack <<<HALF+1, 512, 0, stream>>>(ws0, ws1, ws2, ws3, ws4); // S1..S4

  // ifft along kx + transposed store: S1->T1(ws0), S2->T2(dscr), then
  // S3->T3(ws1), S4->T4(ws2)   (two dispatches to keep in/out disjoint)
  k_inv2 <<<dim3(512,2), 512, 0, stream>>>(ws1, ws2, ws0, dscr);
  k_inv2 <<<dim3(512,2), 512, 0, stream>>>(ws3, ws4, ws1, ws2);

  // bracket (finishes ifftY, regs trick) + fwd fftY -> BR [x][ky']
  k_bracket <<<NF, 256, 0, stream>>>(ws0, dscr, ws1, ws3);

  // fftX + dealias + ifftX fused, transposed write -> ADVt [x][ky']
  k_slabX <<<512, 512, 0, stream>>>(ws3, ws4);

  // final: ifftY of ADVt & T4, combine -> d_out
  k_final <<<NF, 256, 0, stream>>>(ws4, ws2, outF);
}